// Round 4
// baseline (756.120 us; speedup 1.0000x reference)
//
#include <hip/hip_runtime.h>
#include <hip/hip_cooperative_groups.h>

namespace cg = cooperative_groups;

// KMEANS encode+decode: B=65536, G=256, K=512, fp32.
// R9: fixes R8's tile-dispenser bug. R8's `t = atomicAdd(...)` in the loop
// header executed PER-THREAD -> 256 divergent tile ids per block -> mixed-tile
// LDS staging + unprocessed tiles (absmax 0.124). R9 dispenses tiles with a
// single-thread atomicAdd broadcast through LDS (barrier-ordered). All other
// logic is R8 = R6's proven gemm body (M=32, 4 waves, 256 thr) + grid-strided
// prep (bitwise-identical per-column g-ascending arithmetic) + grid.sync +
// R7-validated inline rescue. Per-(row,col) MFMA chain (hh+hl+lh, p ascending,
// same pack layout) and compare/tie order are bitwise-identical to R5-R7, so
// the TAU=2e-3 envelope (absmax 0.0 in R1-R7) is unchanged.
// Fallback: 2-dispatch (prep + fused) if cooperative launch unavailable;
// R1 kernel if no workspace.

constexpr int BATCH  = 65536;
constexpr int GDIM   = 256;   // GEMM K (features)
constexpr int KDIM   = 512;   // GEMM N (codes)
constexpr int NTILES = BATCH / 32;   // 2048 tiles of 32 rows
constexpr float TAU  = 2e-3f;

typedef _Float16 halfx8 __attribute__((ext_vector_type(8)));
typedef float    floatx4 __attribute__((ext_vector_type(4)));

#define SPLIT1(H, L, X) { const _Float16 h_ = (_Float16)(X); (H) = h_; (L) = (_Float16)((X) - (float)h_); }

// ---------------- standalone prep (non-cooperative fallback path) --------
// Packed B layout (verified R4): vec ((nf*8 + p)*4 + q)*16 + n15 holds 8
// halves (k = p*32 + q*8 + j) of column n = nf*16 + n15.

__global__ __launch_bounds__(256)
void prep_kernel(const float* __restrict__ mu, float* __restrict__ muT,
                 float* __restrict__ m2,
                 halfx8* __restrict__ packh, halfx8* __restrict__ packl,
                 int* __restrict__ tile_counter) {
    const int tid = threadIdx.x;
    const int b   = blockIdx.x;
    if (b < 512) {
        const int k = b;
        muT[k * GDIM + tid] = mu[(size_t)tid * KDIM + k];
    } else if (b == 512) {
        if (tid == 0) *tile_counter = NTILES;   // fused kernel grid == NTILES
        float s0 = 0.f, s1 = 0.f;
        for (int g = 0; g < GDIM; ++g) {
            const float a = mu[(size_t)g * KDIM + tid];
            const float c = mu[(size_t)g * KDIM + tid + 256];
            s0 += a * a; s1 += c * c;
        }
        m2[tid] = s0; m2[tid + 256] = s1;
    } else {
        const int gid = (b - 513) * 256 + tid;   // [0, 16384)
        const int n15 = gid & 15;
        const int q   = (gid >> 4) & 3;
        const int p   = (gid >> 6) & 7;
        const int nf  = gid >> 9;
        const int n   = nf * 16 + n15;
        const int k0  = p * 32 + q * 8;
        halfx8 hv, lv;
        #pragma unroll
        for (int j = 0; j < 8; ++j) {
            const float v = mu[(size_t)(k0 + j) * KDIM + n];
            const _Float16 h = (_Float16)v;
            hv[j] = h;
            lv[j] = (_Float16)(v - (float)h);
        }
        packh[gid] = hv;
        packl[gid] = lv;
    }
}

// ---------------- fused: [prep + grid.sync] + gemm/argmin/recon/rescue ----

__global__ __launch_bounds__(256) __attribute__((amdgpu_waves_per_eu(3, 4)))
void gemm_fused(const float* __restrict__ images, const float* __restrict__ mu,
                float* __restrict__ muT, float* __restrict__ m2g,
                halfx8* __restrict__ packh, halfx8* __restrict__ packl,
                float* __restrict__ out, int* __restrict__ tile_counter,
                int do_prep) {
    // A staged as f16 hi/lo split. Row stride 33 vecs (528 B, 16B-aligned):
    // +4-bank skew per row keeps fragment ds_read_b128 conflicts minor.
    constexpr int ASTR = 33;                // halfx8 vecs per row
    __shared__ halfx8 AhL[32 * ASTR];
    __shared__ halfx8 AlL[32 * ASTR];
    __shared__ float sd1[4][32];
    __shared__ float sd2[4][32];
    __shared__ int   sk1[4][32];
    __shared__ int   kb[32];
    __shared__ int   slist[32];
    __shared__ int   scount;
    __shared__ int   snext;
    __shared__ float xs[GDIM];
    __shared__ float rsd[256];
    __shared__ int   rsk[256];

    const int tid  = threadIdx.x;
    const int gid0 = blockIdx.x * 256 + tid;

    // ---- phase 1 (cooperative path only): grid-strided prep ----
    if (do_prep) {
        const int gstep = gridDim.x * 256;
        if (gid0 == 0) *tile_counter = (int)gridDim.x;
        // transpose: same element mapping as prep_kernel
        for (int idx = gid0; idx < KDIM * GDIM; idx += gstep) {
            const int k = idx >> 8, g = idx & 255;
            muT[k * GDIM + g] = mu[(size_t)g * KDIM + k];
        }
        // m2: per-column independent g-ascending fp32 chain (proven order)
        for (int k = gid0; k < KDIM; k += gstep) {
            float s = 0.f;
            for (int g = 0; g < GDIM; ++g) {
                const float a = mu[(size_t)g * KDIM + k];
                s += a * a;
            }
            m2g[k] = s;
        }
        // pack: same per-vec body as prep_kernel
        for (int gidp = gid0; gidp < 16384; gidp += gstep) {
            const int n15 = gidp & 15;
            const int q_  = (gidp >> 4) & 3;
            const int p_  = (gidp >> 6) & 7;
            const int nf_ = gidp >> 9;
            const int n   = nf_ * 16 + n15;
            const int k0  = p_ * 32 + q_ * 8;
            halfx8 hv, lv;
            #pragma unroll
            for (int j = 0; j < 8; ++j) {
                const float v = mu[(size_t)(k0 + j) * KDIM + n];
                const _Float16 h = (_Float16)v;
                hv[j] = h;
                lv[j] = (_Float16)(v - (float)h);
            }
            packh[gidp] = hv;
            packl[gidp] = lv;
        }
        __threadfence();
        cg::this_grid().sync();
    }

    const int wave = tid >> 6;
    const int lane = tid & 63;
    const int q    = lane >> 4;
    const int l15  = lane & 15;

    // ---- phase 2: persistent blocks; tiles dispensed one-thread-atomically --
    int t = blockIdx.x;
    while (t < NTILES) {
        const int m0 = t * 32;

        __syncthreads();            // orders scount/LDS reuse vs prev tile
        if (tid == 0) scount = 0;

        // ---- stage + split A once per tile (each row split exactly once) --
        #pragma unroll
        for (int i = 0; i < 4; ++i) {
            const int cid = tid + i * 256;      // 0..1023
            const int row = cid >> 5;           // 0..31
            const int kc  = cid & 31;           // 8-float chunk within row
            const float* src = images + (size_t)(m0 + row) * GDIM + kc * 8;
            const float4 v0 = *(const float4*)(src);
            const float4 v1 = *(const float4*)(src + 4);
            halfx8 hv, lv;
            SPLIT1(hv[0], lv[0], v0.x)
            SPLIT1(hv[1], lv[1], v0.y)
            SPLIT1(hv[2], lv[2], v0.z)
            SPLIT1(hv[3], lv[3], v0.w)
            SPLIT1(hv[4], lv[4], v1.x)
            SPLIT1(hv[5], lv[5], v1.y)
            SPLIT1(hv[6], lv[6], v1.z)
            SPLIT1(hv[7], lv[7], v1.w)
            AhL[row * ASTR + kc] = hv;
            AlL[row * ASTR + kc] = lv;
        }
        __syncthreads();

        floatx4 acc[2][8] = {};

        // K-loop (R6 body, verbatim): no barriers. A-frag: m = lane&15,
        // k = q*8 + j; vec index for (row, p, q) = row*ASTR + p*4 + q.
        for (int p = 0; p < 8; ++p) {
            halfx8 Ah[2], Al[2];
            #pragma unroll
            for (int mf = 0; mf < 2; ++mf) {
                const int off = (mf * 16 + l15) * ASTR + p * 4 + q;
                Ah[mf] = AhL[off];
                Al[mf] = AlL[off];
            }
            #pragma unroll
            for (int nf = 0; nf < 8; ++nf) {
                const int nfg = wave * 8 + nf;
                const int bidx = ((nfg * 8 + p) * 4 + q) * 16 + l15;
                const halfx8 Bh = packh[bidx];
                const halfx8 Bl = packl[bidx];
                #pragma unroll
                for (int mf = 0; mf < 2; ++mf) {
                    acc[mf][nf] = __builtin_amdgcn_mfma_f32_16x16x32_f16(Ah[mf], Bh, acc[mf][nf], 0, 0, 0);
                    acc[mf][nf] = __builtin_amdgcn_mfma_f32_16x16x32_f16(Ah[mf], Bl, acc[mf][nf], 0, 0, 0);
                    acc[mf][nf] = __builtin_amdgcn_mfma_f32_16x16x32_f16(Al[mf], Bh, acc[mf][nf], 0, 0, 0);
                }
            }
        }

        // ---- epilogue: rank on s = m2 - 2*xm (x2 row-constant) ----
        // C layout (verified R4): col = lane&15 (n_local), row = q*4 + reg.
        float m2v[8];
        #pragma unroll
        for (int nf = 0; nf < 8; ++nf)
            m2v[nf] = m2g[wave * 128 + nf * 16 + l15];

        float d1[2][4], d2[2][4];
        int   k1[2][4];
        #pragma unroll
        for (int mf = 0; mf < 2; ++mf)
            #pragma unroll
            for (int r = 0; r < 4; ++r) { d1[mf][r] = 3.402823466e+38f; d2[mf][r] = 3.402823466e+38f; k1[mf][r] = 0; }

        #pragma unroll
        for (int nf = 0; nf < 8; ++nf) {
            const int kc = wave * 128 + nf * 16 + l15;
            #pragma unroll
            for (int mf = 0; mf < 2; ++mf)
                #pragma unroll
                for (int r = 0; r < 4; ++r) {
                    const float d = m2v[nf] - 2.0f * acc[mf][nf][r];
                    if (d < d1[mf][r]) { d2[mf][r] = d1[mf][r]; d1[mf][r] = d; k1[mf][r] = kc; }
                    else if (d < d2[mf][r]) { d2[mf][r] = d; }
                }
        }

        // butterfly across the 16 lanes of each quad; tie -> lower k
        #pragma unroll
        for (int s = 1; s < 16; s <<= 1) {
            #pragma unroll
            for (int mf = 0; mf < 2; ++mf)
                #pragma unroll
                for (int r = 0; r < 4; ++r) {
                    const float od1 = __shfl_xor(d1[mf][r], s, 64);
                    const int   ok1 = __shfl_xor(k1[mf][r], s, 64);
                    const float od2 = __shfl_xor(d2[mf][r], s, 64);
                    const bool take = (od1 < d1[mf][r]) || (od1 == d1[mf][r] && ok1 < k1[mf][r]);
                    const float loser = take ? d1[mf][r] : od1;
                    if (take) { d1[mf][r] = od1; k1[mf][r] = ok1; }
                    const float m2x = (od2 < d2[mf][r]) ? od2 : d2[mf][r];
                    d2[mf][r] = (loser < m2x) ? loser : m2x;
                }
        }

        if (l15 == 0) {
            #pragma unroll
            for (int mf = 0; mf < 2; ++mf)
                #pragma unroll
                for (int r = 0; r < 4; ++r) {
                    const int ml = mf * 16 + q * 4 + r;     // row within tile
                    sd1[wave][ml] = d1[mf][r];
                    sd2[wave][ml] = d2[mf][r];
                    sk1[wave][ml] = k1[mf][r];
                }
        }
        __syncthreads();

        if (tid < 32) {
            float D1 = sd1[0][tid], D2 = sd2[0][tid];
            int   K1 = sk1[0][tid];
            #pragma unroll
            for (int w = 1; w < 4; ++w) {      // ascending wave = ascending k
                const float od1 = sd1[w][tid], od2 = sd2[w][tid];
                const int   ok1 = sk1[w][tid];
                if (od1 < D1) { D2 = (D1 < od2) ? D1 : od2; D1 = od1; K1 = ok1; }
                else          { D2 = (od1 < D2) ? od1 : D2; }
            }
            kb[tid] = K1;
            if (D2 - D1 < TAU) {
                const int i = atomicAdd(&scount, 1);
                slist[i] = tid;                // local row index
            }
        }
        __syncthreads();

        // ---- fused recon: out rows from muT (L2-hot) ----
        float4* out4 = (float4*)(out + (size_t)m0 * GDIM);
        const float4* muT4 = (const float4*)muT;
        #pragma unroll
        for (int i = 0; i < 8; ++i) {
            const int idx = tid + i * 256;
            const int rr = idx >> 6, cc = idx & 63;
            out4[idx] = muT4[(size_t)kb[rr] * (GDIM / 4) + cc];
        }

        // ---- inline rescue (validated in R7): exact R1-order fp32 ----
        // The first barrier below drains the recon stores (vmcnt(0) before
        // s_barrier), so the overwrite is ordered after recon.
        const int cnt = scount;
        for (int i = 0; i < cnt; ++i) {
            const int row = m0 + slist[i];
            xs[tid] = images[(size_t)row * GDIM + tid];
            __syncthreads();
            // x2 in the proven g-ascending serial order
            float x2 = 0.f;
            for (int g = 0; g < GDIM; ++g) x2 += xs[g] * xs[g];
            // codes tid and tid+256: independent g-ascending fp32 chains
            float sA = 0.f, sB = 0.f;
            for (int g = 0; g < GDIM; ++g) {
                const float xv = xs[g];
                const float* mp = mu + (size_t)g * KDIM;
                sA += xv * mp[tid];
                sB += xv * mp[tid + 256];
            }
            const float dA = (x2 - 2.0f * sA) + m2g[tid];
            const float dB = (x2 - 2.0f * sB) + m2g[tid + 256];
            float bd = dA; int bk = tid;
            if (dB < bd) { bd = dB; bk = tid + 256; }  // strict < keeps lower k
            rsd[tid] = bd; rsk[tid] = bk;
            __syncthreads();
            for (int s = 128; s > 0; s >>= 1) {
                if (tid < s) {
                    const float db = rsd[tid + s]; const int kb2 = rsk[tid + s];
                    if (db < rsd[tid] || (db == rsd[tid] && kb2 < rsk[tid])) { rsd[tid] = db; rsk[tid] = kb2; }
                }
                __syncthreads();
            }
            const int kwin = rsk[0];
            out[(size_t)row * GDIM + tid] = muT[(size_t)kwin * GDIM + tid];
            __syncthreads();
        }

        // ---- next tile: ONE thread atomically claims, broadcast via LDS ----
        __syncthreads();
        if (tid == 0) snext = atomicAdd(tile_counter, 1);
        __syncthreads();
        t = snext;
    }
}

// ---------------- fallback (R1 kernel, no workspace) ----------------

constexpr int FROWS = 64, FXSTR = GDIM + 1;

__global__ __launch_bounds__(256)
void kmeans_fallback(const float* __restrict__ images, const float* __restrict__ mu,
                     float* __restrict__ out) {
    __shared__ float xsf[FROWS * FXSTR];
    __shared__ float m2s[KDIM];
    __shared__ float bd_s[4][FROWS];
    __shared__ int   bk_s[4][FROWS];
    __shared__ int   kbest_s[FROWS];
    const int tid = threadIdx.x;
    const long long b0 = (long long)blockIdx.x * FROWS;
    {
        const float4* img4 = (const float4*)(images + b0 * GDIM);
        #pragma unroll
        for (int i = 0; i < 16; ++i) {
            const int idx = tid + i * 256;
            const int r = idx >> 6, c = idx & 63;
            const float4 v = img4[idx];
            float* dst = &xsf[r * FXSTR + c * 4];
            dst[0] = v.x; dst[1] = v.y; dst[2] = v.z; dst[3] = v.w;
        }
    }
    {
        float s0 = 0.f, s1 = 0.f;
        for (int g = 0; g < GDIM; ++g) {
            const float a = mu[(size_t)g * KDIM + tid];
            const float b = mu[(size_t)g * KDIM + tid + 256];
            s0 += a * a; s1 += b * b;
        }
        m2s[tid] = s0; m2s[tid + 256] = s1;
    }
    __syncthreads();
    const int r = tid & (FROWS - 1), ch = tid >> 6;
    const float* xrow = &xsf[r * FXSTR];
    float x2 = 0.f;
    #pragma unroll 8
    for (int g = 0; g < GDIM; ++g) x2 += xrow[g] * xrow[g];
    float bestd = 3.402823466e+38f; int bestk = 0;
    const int k0base = ch * (KDIM / 4);
    for (int kt = 0; kt < KDIM / 4; kt += 8) {
        const int k0 = k0base + kt;
        float a8[8];
        #pragma unroll
        for (int j = 0; j < 8; ++j) a8[j] = 0.f;
        const float* mp = mu + k0;
        #pragma unroll 4
        for (int g = 0; g < GDIM; ++g) {
            const float xv = xrow[g];
            const float4 a = *(const float4*)(mp + (size_t)g * KDIM);
            const float4 b = *(const float4*)(mp + (size_t)g * KDIM + 4);
            a8[0] += xv * a.x; a8[1] += xv * a.y; a8[2] += xv * a.z; a8[3] += xv * a.w;
            a8[4] += xv * b.x; a8[5] += xv * b.y; a8[6] += xv * b.z; a8[7] += xv * b.w;
        }
        #pragma unroll
        for (int j = 0; j < 8; ++j) {
            const float t = x2 - 2.0f * a8[j];
            const float d = t + m2s[k0 + j];
            if (d < bestd) { bestd = d; bestk = k0 + j; }
        }
    }
    bd_s[ch][r] = bestd; bk_s[ch][r] = bestk;
    __syncthreads();
    if (tid < FROWS) {
        float bd = bd_s[0][tid]; int bk = bk_s[0][tid];
        #pragma unroll
        for (int c = 1; c < 4; ++c)
            if (bd_s[c][tid] < bd) { bd = bd_s[c][tid]; bk = bk_s[c][tid]; }
        kbest_s[tid] = bk;
    }
    __syncthreads();
    for (int i = tid; i < FROWS * GDIM; i += 256) {
        const int rr = i >> 8, gg = i & (GDIM - 1);
        out[b0 * GDIM + i] = mu[(size_t)gg * KDIM + kbest_s[rr]];
    }
}

// ---------------- launch ----------------

extern "C" void kernel_launch(void* const* d_in, const int* in_sizes, int n_in,
                              void* d_out, int out_size, void* d_ws, size_t ws_size,
                              hipStream_t stream) {
    const float* images = (const float*)d_in[0];
    const float* mu     = (const float*)d_in[1];
    float* out = (float*)d_out;

    float* ws     = (float*)d_ws;
    float* muT    = ws;                          // 131072 floats
    float* m2     = ws + 131072;                 // 512
    halfx8* packh = (halfx8*)(ws + 131584);      // 65536 floats (16384 vecs)
    halfx8* packl = (halfx8*)(ws + 197120);      // 65536 floats
    int*   tile_counter = (int*)(ws + 262656);   // 16
    const size_t need = (size_t)262672 * sizeof(float);

    if (d_ws != nullptr && ws_size >= need) {
        // Query cooperative capacity once (host-side computation; no stream op).
        static int coopBlocks = -2;
        if (coopBlocks == -2) {
            int nb = 0;
            hipError_t e = hipOccupancyMaxActiveBlocksPerMultiprocessor(&nb, gemm_fused, 256, 0);
            coopBlocks = (e == hipSuccess && nb > 0) ? nb : -1;
        }
        if (coopBlocks > 0) {
            int grid = coopBlocks * 256;         // 256 CUs on MI355X
            if (grid > NTILES) grid = NTILES;
            int do_prep = 1;
            void* args[] = { (void*)&images, (void*)&mu, (void*)&muT, (void*)&m2,
                             (void*)&packh, (void*)&packl, (void*)&out,
                             (void*)&tile_counter, (void*)&do_prep };
            hipError_t e = hipLaunchCooperativeKernel((const void*)gemm_fused,
                                                      dim3(grid), dim3(256),
                                                      args, 0, stream);
            if (e == hipSuccess) return;
        }
        // Non-cooperative fallback: 2 dispatches (prep sets tile_counter).
        prep_kernel<<<577, 256, 0, stream>>>(mu, muT, m2, packh, packl, tile_counter);
        gemm_fused<<<NTILES, 256, 0, stream>>>(images, mu, muT, m2, packh, packl,
                                               out, tile_counter, 0);
    } else {
        kmeans_fallback<<<BATCH / 64, 256, 0, stream>>>(images, mu, out);
    }
}

// Round 5
// 317.330 us; speedup vs baseline: 2.3828x; 2.3828x over previous
//
#include <hip/hip_runtime.h>

// KMEANS encode+decode: B=65536, G=256, K=512, fp32.
// R10: single plain dispatch. R9's persistent/cooperative structure caused
// +350MB of symmetric HBM traffic (490us) and is abandoned. R10 = R6's proven
// 96.7us gemm body (static grid, 1 tile/block, M=32, 4 waves, 256 thr) +
// R7/R9-validated inline rescue + in-kernel ticket-gated prep:
//   - first 129 blocks TO EXECUTE (device-scope ticket) each do one prep
//     slice (64 pack / 1 m2 / 64 muT), element-identical to the proven
//     prep_kernel arithmetic; then __threadfence (agent release, L2 wb) +
//     release-increment of done.
//   - every block spins (tid0, relaxed agent loads) until done==129, then
//     one __threadfence (acquire, L1/L2 inval) before reading pack/m2/muT.
//   Producers are running blocks by construction (ticket = execution order);
//   resident capacity (>=768 blocks) >> 129 -> no deadlock. Guideline 16
//   pattern: device-scope atomics + fences for inter-block communication.
// ticket/done zeroed by a 16B hipMemsetAsync on the stream (capturable).
// Per-(row,col) MFMA chain (hh+hl+lh, p ascending, same pack layout) and
// compare/tie order are bitwise-identical to R5-R9, so the TAU=2e-3 rescue
// envelope (absmax 0.0 in R1-R7, R9) is unchanged.

constexpr int BATCH  = 65536;
constexpr int GDIM   = 256;   // GEMM K (features)
constexpr int KDIM   = 512;   // GEMM N (codes)
constexpr int NTILES = BATCH / 32;   // 2048 tiles of 32 rows
constexpr int NPREP  = 129;   // 64 pack + 1 m2 + 64 muT slices
constexpr float TAU  = 2e-3f;

typedef _Float16 halfx8 __attribute__((ext_vector_type(8)));
typedef float    floatx4 __attribute__((ext_vector_type(4)));

#define SPLIT1(H, L, X) { const _Float16 h_ = (_Float16)(X); (H) = h_; (L) = (_Float16)((X) - (float)h_); }

// ---------------- fused: gated prep + gemm/argmin/recon/rescue ----------

__global__ __launch_bounds__(256) __attribute__((amdgpu_waves_per_eu(3, 4)))
void gemm_gated(const float* __restrict__ images, const float* __restrict__ mu,
                float* __restrict__ muT, float* __restrict__ m2g,
                halfx8* __restrict__ packh, halfx8* __restrict__ packl,
                float* __restrict__ out, int* __restrict__ gate) {
    // A staged as f16 hi/lo split. Row stride 33 vecs (528 B, 16B-aligned):
    // +4-bank skew per row keeps fragment ds_read_b128 conflicts minor.
    constexpr int ASTR = 33;                // halfx8 vecs per row
    __shared__ halfx8 AhL[32 * ASTR];
    __shared__ halfx8 AlL[32 * ASTR];
    __shared__ float sd1[4][32];
    __shared__ float sd2[4][32];
    __shared__ int   sk1[4][32];
    __shared__ int   kb[32];
    __shared__ int   slist[32];
    __shared__ int   scount;
    __shared__ int   sticket;
    __shared__ float xs[GDIM];
    __shared__ float rsd[256];
    __shared__ int   rsk[256];

    const int tid = threadIdx.x;

    // ---- ticket: first NPREP blocks to execute become producers ----
    if (tid == 0) {
        sticket = __hip_atomic_fetch_add(&gate[0], 1, __ATOMIC_RELAXED,
                                         __HIP_MEMORY_SCOPE_AGENT);
        scount = 0;
    }
    __syncthreads();
    const int slice = sticket;

    if (slice < NPREP) {
        if (slice < 64) {
            // pack slice: identical per-element body to the proven prep.
            // vec ((nf*8 + p)*4 + q)*16 + n15 holds 8 halves (k = p*32+q*8+j)
            // of column n = nf*16 + n15.
            const int gid = slice * 256 + tid;   // [0, 16384)
            const int n15 = gid & 15;
            const int q_  = (gid >> 4) & 3;
            const int p_  = (gid >> 6) & 7;
            const int nf_ = gid >> 9;
            const int n   = nf_ * 16 + n15;
            const int k0  = p_ * 32 + q_ * 8;
            halfx8 hv, lv;
            #pragma unroll
            for (int j = 0; j < 8; ++j) {
                const float v = mu[(size_t)(k0 + j) * KDIM + n];
                const _Float16 h = (_Float16)v;
                hv[j] = h;
                lv[j] = (_Float16)(v - (float)h);
            }
            packh[gid] = hv;
            packl[gid] = lv;
        } else if (slice == 64) {
            // m2: per-column independent g-ascending fp32 chain (proven order)
            float s0 = 0.f, s1 = 0.f;
            for (int g = 0; g < GDIM; ++g) {
                const float a = mu[(size_t)g * KDIM + tid];
                const float c = mu[(size_t)g * KDIM + tid + 256];
                s0 += a * a; s1 += c * c;
            }
            m2g[tid] = s0; m2g[tid + 256] = s1;
        } else {
            // muT slice: 8 k-columns, same element mapping as proven prep
            const int kbase = (slice - 65) * 8;
            #pragma unroll
            for (int j = 0; j < 8; ++j) {
                const int k = kbase + j;
                muT[k * GDIM + tid] = mu[(size_t)tid * KDIM + k];
            }
        }
        __syncthreads();                      // all producer stores drained
        if (tid == 0) {
            __threadfence();                  // agent release: L2 writeback
            __hip_atomic_fetch_add(&gate[1], 1, __ATOMIC_RELEASE,
                                   __HIP_MEMORY_SCOPE_AGENT);
        }
    }

    // ---- gate: wait for all prep slices, then acquire (L1/L2 inval) ----
    if (tid == 0) {
        while (__hip_atomic_load(&gate[1], __ATOMIC_RELAXED,
                                 __HIP_MEMORY_SCOPE_AGENT) < NPREP)
            __builtin_amdgcn_s_sleep(16);
        __threadfence();                      // acquire side
    }
    __syncthreads();

    const int wave = tid >> 6;
    const int lane = tid & 63;
    const int q    = lane >> 4;
    const int l15  = lane & 15;
    const int m0   = blockIdx.x * 32;

    // ---- stage + split A once per tile (each row split exactly once) ----
    #pragma unroll
    for (int i = 0; i < 4; ++i) {
        const int cid = tid + i * 256;      // 0..1023
        const int row = cid >> 5;           // 0..31
        const int kc  = cid & 31;           // 8-float chunk within row
        const float* src = images + (size_t)(m0 + row) * GDIM + kc * 8;
        const float4 v0 = *(const float4*)(src);
        const float4 v1 = *(const float4*)(src + 4);
        halfx8 hv, lv;
        SPLIT1(hv[0], lv[0], v0.x)
        SPLIT1(hv[1], lv[1], v0.y)
        SPLIT1(hv[2], lv[2], v0.z)
        SPLIT1(hv[3], lv[3], v0.w)
        SPLIT1(hv[4], lv[4], v1.x)
        SPLIT1(hv[5], lv[5], v1.y)
        SPLIT1(hv[6], lv[6], v1.z)
        SPLIT1(hv[7], lv[7], v1.w)
        AhL[row * ASTR + kc] = hv;
        AlL[row * ASTR + kc] = lv;
    }
    __syncthreads();

    floatx4 acc[2][8] = {};

    // K-loop (R6 body, verbatim): no barriers. A-frag: m = lane&15,
    // k = q*8 + j; vec index for (row, p, q) = row*ASTR + p*4 + q.
    for (int p = 0; p < 8; ++p) {
        halfx8 Ah[2], Al[2];
        #pragma unroll
        for (int mf = 0; mf < 2; ++mf) {
            const int off = (mf * 16 + l15) * ASTR + p * 4 + q;
            Ah[mf] = AhL[off];
            Al[mf] = AlL[off];
        }
        #pragma unroll
        for (int nf = 0; nf < 8; ++nf) {
            const int nfg = wave * 8 + nf;
            const int bidx = ((nfg * 8 + p) * 4 + q) * 16 + l15;
            const halfx8 Bh = packh[bidx];
            const halfx8 Bl = packl[bidx];
            #pragma unroll
            for (int mf = 0; mf < 2; ++mf) {
                acc[mf][nf] = __builtin_amdgcn_mfma_f32_16x16x32_f16(Ah[mf], Bh, acc[mf][nf], 0, 0, 0);
                acc[mf][nf] = __builtin_amdgcn_mfma_f32_16x16x32_f16(Ah[mf], Bl, acc[mf][nf], 0, 0, 0);
                acc[mf][nf] = __builtin_amdgcn_mfma_f32_16x16x32_f16(Al[mf], Bh, acc[mf][nf], 0, 0, 0);
            }
        }
    }

    // ---- epilogue: rank on s = m2 - 2*xm (x2 row-constant) ----
    // C layout (verified R4): col = lane&15 (n_local), row = q*4 + reg.
    float m2v[8];
    #pragma unroll
    for (int nf = 0; nf < 8; ++nf)
        m2v[nf] = m2g[wave * 128 + nf * 16 + l15];

    float d1[2][4], d2[2][4];
    int   k1[2][4];
    #pragma unroll
    for (int mf = 0; mf < 2; ++mf)
        #pragma unroll
        for (int r = 0; r < 4; ++r) { d1[mf][r] = 3.402823466e+38f; d2[mf][r] = 3.402823466e+38f; k1[mf][r] = 0; }

    #pragma unroll
    for (int nf = 0; nf < 8; ++nf) {
        const int kc = wave * 128 + nf * 16 + l15;
        #pragma unroll
        for (int mf = 0; mf < 2; ++mf)
            #pragma unroll
            for (int r = 0; r < 4; ++r) {
                const float d = m2v[nf] - 2.0f * acc[mf][nf][r];
                if (d < d1[mf][r]) { d2[mf][r] = d1[mf][r]; d1[mf][r] = d; k1[mf][r] = kc; }
                else if (d < d2[mf][r]) { d2[mf][r] = d; }
            }
    }

    // butterfly across the 16 lanes of each quad; tie -> lower k
    #pragma unroll
    for (int s = 1; s < 16; s <<= 1) {
        #pragma unroll
        for (int mf = 0; mf < 2; ++mf)
            #pragma unroll
            for (int r = 0; r < 4; ++r) {
                const float od1 = __shfl_xor(d1[mf][r], s, 64);
                const int   ok1 = __shfl_xor(k1[mf][r], s, 64);
                const float od2 = __shfl_xor(d2[mf][r], s, 64);
                const bool take = (od1 < d1[mf][r]) || (od1 == d1[mf][r] && ok1 < k1[mf][r]);
                const float loser = take ? d1[mf][r] : od1;
                if (take) { d1[mf][r] = od1; k1[mf][r] = ok1; }
                const float m2x = (od2 < d2[mf][r]) ? od2 : d2[mf][r];
                d2[mf][r] = (loser < m2x) ? loser : m2x;
            }
    }

    if (l15 == 0) {
        #pragma unroll
        for (int mf = 0; mf < 2; ++mf)
            #pragma unroll
            for (int r = 0; r < 4; ++r) {
                const int ml = mf * 16 + q * 4 + r;     // row within tile
                sd1[wave][ml] = d1[mf][r];
                sd2[wave][ml] = d2[mf][r];
                sk1[wave][ml] = k1[mf][r];
            }
    }
    __syncthreads();

    if (tid < 32) {
        float D1 = sd1[0][tid], D2 = sd2[0][tid];
        int   K1 = sk1[0][tid];
        #pragma unroll
        for (int w = 1; w < 4; ++w) {          // ascending wave = ascending k
            const float od1 = sd1[w][tid], od2 = sd2[w][tid];
            const int   ok1 = sk1[w][tid];
            if (od1 < D1) { D2 = (D1 < od2) ? D1 : od2; D1 = od1; K1 = ok1; }
            else          { D2 = (od1 < D2) ? od1 : D2; }
        }
        kb[tid] = K1;
        if (D2 - D1 < TAU) {
            const int i = atomicAdd(&scount, 1);
            slist[i] = tid;                    // local row index
        }
    }
    __syncthreads();

    // ---- fused recon: out rows from muT (L2-hot) ----
    float4* out4 = (float4*)(out + (size_t)m0 * GDIM);
    const float4* muT4 = (const float4*)muT;
    #pragma unroll
    for (int i = 0; i < 8; ++i) {
        const int idx = tid + i * 256;
        const int rr = idx >> 6, cc = idx & 63;
        out4[idx] = muT4[(size_t)kb[rr] * (GDIM / 4) + cc];
    }

    // ---- inline rescue (validated R7/R9): exact R1-order fp32 ----
    // The first barrier below drains the recon stores (vmcnt(0) before
    // s_barrier), so the overwrite is ordered after recon.
    const int cnt = scount;
    for (int i = 0; i < cnt; ++i) {
        const int row = m0 + slist[i];
        xs[tid] = images[(size_t)row * GDIM + tid];
        __syncthreads();
        // x2 in the proven g-ascending serial order
        float x2 = 0.f;
        for (int g = 0; g < GDIM; ++g) x2 += xs[g] * xs[g];
        // codes tid and tid+256: independent g-ascending fp32 chains
        float sA = 0.f, sB = 0.f;
        for (int g = 0; g < GDIM; ++g) {
            const float xv = xs[g];
            const float* mp = mu + (size_t)g * KDIM;
            sA += xv * mp[tid];
            sB += xv * mp[tid + 256];
        }
        const float dA = (x2 - 2.0f * sA) + m2g[tid];
        const float dB = (x2 - 2.0f * sB) + m2g[tid + 256];
        float bd = dA; int bk = tid;
        if (dB < bd) { bd = dB; bk = tid + 256; }      // strict < keeps lower k
        rsd[tid] = bd; rsk[tid] = bk;
        __syncthreads();
        for (int s = 128; s > 0; s >>= 1) {
            if (tid < s) {
                const float db = rsd[tid + s]; const int kb2 = rsk[tid + s];
                if (db < rsd[tid] || (db == rsd[tid] && kb2 < rsk[tid])) { rsd[tid] = db; rsk[tid] = kb2; }
            }
            __syncthreads();
        }
        const int kwin = rsk[0];
        out[(size_t)row * GDIM + tid] = muT[(size_t)kwin * GDIM + tid];
        __syncthreads();
    }
}

// ---------------- fallback (R1 kernel, no workspace) ----------------

constexpr int FROWS = 64, FXSTR = GDIM + 1;

__global__ __launch_bounds__(256)
void kmeans_fallback(const float* __restrict__ images, const float* __restrict__ mu,
                     float* __restrict__ out) {
    __shared__ float xsf[FROWS * FXSTR];
    __shared__ float m2s[KDIM];
    __shared__ float bd_s[4][FROWS];
    __shared__ int   bk_s[4][FROWS];
    __shared__ int   kbest_s[FROWS];
    const int tid = threadIdx.x;
    const long long b0 = (long long)blockIdx.x * FROWS;
    {
        const float4* img4 = (const float4*)(images + b0 * GDIM);
        #pragma unroll
        for (int i = 0; i < 16; ++i) {
            const int idx = tid + i * 256;
            const int r = idx >> 6, c = idx & 63;
            const float4 v = img4[idx];
            float* dst = &xsf[r * FXSTR + c * 4];
            dst[0] = v.x; dst[1] = v.y; dst[2] = v.z; dst[3] = v.w;
        }
    }
    {
        float s0 = 0.f, s1 = 0.f;
        for (int g = 0; g < GDIM; ++g) {
            const float a = mu[(size_t)g * KDIM + tid];
            const float b = mu[(size_t)g * KDIM + tid + 256];
            s0 += a * a; s1 += b * b;
        }
        m2s[tid] = s0; m2s[tid + 256] = s1;
    }
    __syncthreads();
    const int r = tid & (FROWS - 1), ch = tid >> 6;
    const float* xrow = &xsf[r * FXSTR];
    float x2 = 0.f;
    #pragma unroll 8
    for (int g = 0; g < GDIM; ++g) x2 += xrow[g] * xrow[g];
    float bestd = 3.402823466e+38f; int bestk = 0;
    const int k0base = ch * (KDIM / 4);
    for (int kt = 0; kt < KDIM / 4; kt += 8) {
        const int k0 = k0base + kt;
        float a8[8];
        #pragma unroll
        for (int j = 0; j < 8; ++j) a8[j] = 0.f;
        const float* mp = mu + k0;
        #pragma unroll 4
        for (int g = 0; g < GDIM; ++g) {
            const float xv = xrow[g];
            const float4 a = *(const float4*)(mp + (size_t)g * KDIM);
            const float4 b = *(const float4*)(mp + (size_t)g * KDIM + 4);
            a8[0] += xv * a.x; a8[1] += xv * a.y; a8[2] += xv * a.z; a8[3] += xv * a.w;
            a8[4] += xv * b.x; a8[5] += xv * b.y; a8[6] += xv * b.z; a8[7] += xv * b.w;
        }
        #pragma unroll
        for (int j = 0; j < 8; ++j) {
            const float t = x2 - 2.0f * a8[j];
            const float d = t + m2s[k0 + j];
            if (d < bestd) { bestd = d; bestk = k0 + j; }
        }
    }
    bd_s[ch][r] = bestd; bk_s[ch][r] = bestk;
    __syncthreads();
    if (tid < FROWS) {
        float bd = bd_s[0][tid]; int bk = bk_s[0][tid];
        #pragma unroll
        for (int c = 1; c < 4; ++c)
            if (bd_s[c][tid] < bd) { bd = bd_s[c][tid]; bk = bk_s[c][tid]; }
        kbest_s[tid] = bk;
    }
    __syncthreads();
    for (int i = tid; i < FROWS * GDIM; i += 256) {
        const int rr = i >> 8, gg = i & (GDIM - 1);
        out[b0 * GDIM + i] = mu[(size_t)gg * KDIM + kbest_s[rr]];
    }
}

// ---------------- launch ----------------

extern "C" void kernel_launch(void* const* d_in, const int* in_sizes, int n_in,
                              void* d_out, int out_size, void* d_ws, size_t ws_size,
                              hipStream_t stream) {
    const float* images = (const float*)d_in[0];
    const float* mu     = (const float*)d_in[1];
    float* out = (float*)d_out;

    float* ws     = (float*)d_ws;
    float* muT    = ws;                          // 131072 floats
    float* m2     = ws + 131072;                 // 512
    halfx8* packh = (halfx8*)(ws + 131584);      // 65536 floats (16384 vecs)
    halfx8* packl = (halfx8*)(ws + 197120);      // 65536 floats
    int*   gate   = (int*)(ws + 262656);         // 16 ints: [0]=ticket [1]=done
    const size_t need = (size_t)262672 * sizeof(float);

    if (d_ws != nullptr && ws_size >= need) {
        hipMemsetAsync(gate, 0, 16, stream);     // zero ticket/done (captured)
        gemm_gated<<<NTILES, 256, 0, stream>>>(images, mu, muT, m2,
                                               packh, packl, out, gate);
    } else {
        kmeans_fallback<<<BATCH / 64, 256, 0, stream>>>(images, mu, out);
    }
}

// Round 6
// 187.922 us; speedup vs baseline: 4.0236x; 1.6886x over previous
//
#include <hip/hip_runtime.h>

// KMEANS encode+decode: B=65536, G=256, K=512, fp32.
// R11: recombination of proven parts, 2 dispatches.
//   dispatch 1: prep_kernel (R6-proven, ~10us): muT transpose + m2 (proven
//               g-ascending order) + f16 hi/lo pack.
//   dispatch 2: R6's 96.7us gemm body VERBATIM (M=32 tiles, 4 waves, 256 thr,
//               3 waves/EU, LDS-staged split-A, barrier-free K-loop) +
//               R7/R9-validated inline rescue (block-local flagged rows,
//               exact R1-order fp32 recompute).
// R10 post-mortem: single-dispatch gating requires an agent-acquire fence per
// block, which invalidates the XCD's L2 (per-XCD L2 non-coherent) and wiped
// the pack working set -> 2.5x slowdown with clean HBM counters. 2 dispatches
// avoid all cross-block coherence machinery.
// Per-(row,col) MFMA chain (hh+hl+lh, p ascending, same pack layout) and
// compare/tie order are bitwise-identical to R5-R10, so the TAU=2e-3 rescue
// envelope (absmax 0.0 in R1-R7, R9, R10) is unchanged.

constexpr int BATCH  = 65536;
constexpr int GDIM   = 256;   // GEMM K (features)
constexpr int KDIM   = 512;   // GEMM N (codes)
constexpr int NTILES = BATCH / 32;   // 2048 tiles of 32 rows
constexpr float TAU  = 2e-3f;

typedef _Float16 halfx8 __attribute__((ext_vector_type(8)));
typedef float    floatx4 __attribute__((ext_vector_type(4)));

#define SPLIT1(H, L, X) { const _Float16 h_ = (_Float16)(X); (H) = h_; (L) = (_Float16)((X) - (float)h_); }

// ---------------- prep: transpose + m2 + pack (R6-proven) ----------------
// Packed B layout (verified R4): vec ((nf*8 + p)*4 + q)*16 + n15 holds 8
// halves (k = p*32 + q*8 + j) of column n = nf*16 + n15.

__global__ __launch_bounds__(256)
void prep_kernel(const float* __restrict__ mu, float* __restrict__ muT,
                 float* __restrict__ m2,
                 halfx8* __restrict__ packh, halfx8* __restrict__ packl) {
    const int tid = threadIdx.x;
    const int b   = blockIdx.x;
    if (b < 512) {
        const int k = b;
        muT[k * GDIM + tid] = mu[(size_t)tid * KDIM + k];
    } else if (b == 512) {
        float s0 = 0.f, s1 = 0.f;
        for (int g = 0; g < GDIM; ++g) {
            const float a = mu[(size_t)g * KDIM + tid];
            const float c = mu[(size_t)g * KDIM + tid + 256];
            s0 += a * a; s1 += c * c;
        }
        m2[tid] = s0; m2[tid + 256] = s1;
    } else {
        const int gid = (b - 513) * 256 + tid;   // [0, 16384)
        const int n15 = gid & 15;
        const int q   = (gid >> 4) & 3;
        const int p   = (gid >> 6) & 7;
        const int nf  = gid >> 9;
        const int n   = nf * 16 + n15;
        const int k0  = p * 32 + q * 8;
        halfx8 hv, lv;
        #pragma unroll
        for (int j = 0; j < 8; ++j) {
            const float v = mu[(size_t)(k0 + j) * KDIM + n];
            const _Float16 h = (_Float16)v;
            hv[j] = h;
            lv[j] = (_Float16)(v - (float)h);
        }
        packh[gid] = hv;
        packl[gid] = lv;
    }
}

// ---------------- main: gemm + argmin + recon + inline rescue ------------

__global__ __launch_bounds__(256) __attribute__((amdgpu_waves_per_eu(3, 4)))
void gemm_argmin_mfma(const float* __restrict__ images, const float* __restrict__ mu,
                      const halfx8* __restrict__ packh,
                      const halfx8* __restrict__ packl,
                      const float* __restrict__ m2g,
                      const float* __restrict__ muT,
                      float* __restrict__ out) {
    // A staged as f16 hi/lo split. Row stride 33 vecs (528 B, 16B-aligned):
    // +4-bank skew per row keeps fragment ds_read_b128 conflicts minor.
    constexpr int ASTR = 33;                // halfx8 vecs per row
    __shared__ halfx8 AhL[32 * ASTR];
    __shared__ halfx8 AlL[32 * ASTR];
    __shared__ float sd1[4][32];
    __shared__ float sd2[4][32];
    __shared__ int   sk1[4][32];
    __shared__ int   kb[32];
    __shared__ int   slist[32];
    __shared__ int   scount;
    __shared__ float xs[GDIM];
    __shared__ float rsd[256];
    __shared__ int   rsk[256];

    const int tid  = threadIdx.x;
    const int wave = tid >> 6;
    const int lane = tid & 63;
    const int q    = lane >> 4;
    const int l15  = lane & 15;
    const int m0   = blockIdx.x * 32;

    if (tid == 0) scount = 0;

    // ---- stage + split A once per tile (each row split exactly once) ----
    #pragma unroll
    for (int i = 0; i < 4; ++i) {
        const int cid = tid + i * 256;      // 0..1023
        const int row = cid >> 5;           // 0..31
        const int kc  = cid & 31;           // 8-float chunk within row
        const float* src = images + (size_t)(m0 + row) * GDIM + kc * 8;
        const float4 v0 = *(const float4*)(src);
        const float4 v1 = *(const float4*)(src + 4);
        halfx8 hv, lv;
        SPLIT1(hv[0], lv[0], v0.x)
        SPLIT1(hv[1], lv[1], v0.y)
        SPLIT1(hv[2], lv[2], v0.z)
        SPLIT1(hv[3], lv[3], v0.w)
        SPLIT1(hv[4], lv[4], v1.x)
        SPLIT1(hv[5], lv[5], v1.y)
        SPLIT1(hv[6], lv[6], v1.z)
        SPLIT1(hv[7], lv[7], v1.w)
        AhL[row * ASTR + kc] = hv;
        AlL[row * ASTR + kc] = lv;
    }
    __syncthreads();

    floatx4 acc[2][8] = {};

    // K-loop (R6 body, verbatim): no barriers. A-frag: m = lane&15,
    // k = q*8 + j; vec index for (row, p, q) = row*ASTR + p*4 + q.
    for (int p = 0; p < 8; ++p) {
        halfx8 Ah[2], Al[2];
        #pragma unroll
        for (int mf = 0; mf < 2; ++mf) {
            const int off = (mf * 16 + l15) * ASTR + p * 4 + q;
            Ah[mf] = AhL[off];
            Al[mf] = AlL[off];
        }
        #pragma unroll
        for (int nf = 0; nf < 8; ++nf) {
            const int nfg = wave * 8 + nf;
            const int bidx = ((nfg * 8 + p) * 4 + q) * 16 + l15;
            const halfx8 Bh = packh[bidx];
            const halfx8 Bl = packl[bidx];
            #pragma unroll
            for (int mf = 0; mf < 2; ++mf) {
                acc[mf][nf] = __builtin_amdgcn_mfma_f32_16x16x32_f16(Ah[mf], Bh, acc[mf][nf], 0, 0, 0);
                acc[mf][nf] = __builtin_amdgcn_mfma_f32_16x16x32_f16(Ah[mf], Bl, acc[mf][nf], 0, 0, 0);
                acc[mf][nf] = __builtin_amdgcn_mfma_f32_16x16x32_f16(Al[mf], Bh, acc[mf][nf], 0, 0, 0);
            }
        }
    }

    // ---- epilogue: rank on s = m2 - 2*xm (x2 row-constant) ----
    // C layout (verified R4): col = lane&15 (n_local), row = q*4 + reg.
    float m2v[8];
    #pragma unroll
    for (int nf = 0; nf < 8; ++nf)
        m2v[nf] = m2g[wave * 128 + nf * 16 + l15];

    float d1[2][4], d2[2][4];
    int   k1[2][4];
    #pragma unroll
    for (int mf = 0; mf < 2; ++mf)
        #pragma unroll
        for (int r = 0; r < 4; ++r) { d1[mf][r] = 3.402823466e+38f; d2[mf][r] = 3.402823466e+38f; k1[mf][r] = 0; }

    #pragma unroll
    for (int nf = 0; nf < 8; ++nf) {
        const int kc = wave * 128 + nf * 16 + l15;
        #pragma unroll
        for (int mf = 0; mf < 2; ++mf)
            #pragma unroll
            for (int r = 0; r < 4; ++r) {
                const float d = m2v[nf] - 2.0f * acc[mf][nf][r];
                if (d < d1[mf][r]) { d2[mf][r] = d1[mf][r]; d1[mf][r] = d; k1[mf][r] = kc; }
                else if (d < d2[mf][r]) { d2[mf][r] = d; }
            }
    }

    // butterfly across the 16 lanes of each quad; tie -> lower k
    #pragma unroll
    for (int s = 1; s < 16; s <<= 1) {
        #pragma unroll
        for (int mf = 0; mf < 2; ++mf)
            #pragma unroll
            for (int r = 0; r < 4; ++r) {
                const float od1 = __shfl_xor(d1[mf][r], s, 64);
                const int   ok1 = __shfl_xor(k1[mf][r], s, 64);
                const float od2 = __shfl_xor(d2[mf][r], s, 64);
                const bool take = (od1 < d1[mf][r]) || (od1 == d1[mf][r] && ok1 < k1[mf][r]);
                const float loser = take ? d1[mf][r] : od1;
                if (take) { d1[mf][r] = od1; k1[mf][r] = ok1; }
                const float m2x = (od2 < d2[mf][r]) ? od2 : d2[mf][r];
                d2[mf][r] = (loser < m2x) ? loser : m2x;
            }
    }

    if (l15 == 0) {
        #pragma unroll
        for (int mf = 0; mf < 2; ++mf)
            #pragma unroll
            for (int r = 0; r < 4; ++r) {
                const int ml = mf * 16 + q * 4 + r;     // row within tile
                sd1[wave][ml] = d1[mf][r];
                sd2[wave][ml] = d2[mf][r];
                sk1[wave][ml] = k1[mf][r];
            }
    }
    __syncthreads();

    if (tid < 32) {
        float D1 = sd1[0][tid], D2 = sd2[0][tid];
        int   K1 = sk1[0][tid];
        #pragma unroll
        for (int w = 1; w < 4; ++w) {          // ascending wave = ascending k
            const float od1 = sd1[w][tid], od2 = sd2[w][tid];
            const int   ok1 = sk1[w][tid];
            if (od1 < D1) { D2 = (D1 < od2) ? D1 : od2; D1 = od1; K1 = ok1; }
            else          { D2 = (od1 < D2) ? od1 : D2; }
        }
        kb[tid] = K1;
        if (D2 - D1 < TAU) {
            const int i = atomicAdd(&scount, 1);
            slist[i] = tid;                    // local row index
        }
    }
    __syncthreads();

    // ---- fused recon: out rows from muT (L2-hot) ----
    float4* out4 = (float4*)(out + (size_t)m0 * GDIM);
    const float4* muT4 = (const float4*)muT;
    #pragma unroll
    for (int i = 0; i < 8; ++i) {
        const int idx = tid + i * 256;
        const int rr = idx >> 6, cc = idx & 63;
        out4[idx] = muT4[(size_t)kb[rr] * (GDIM / 4) + cc];
    }

    // ---- inline rescue (validated R7/R9/R10): exact R1-order fp32 ----
    // The first barrier below drains the recon stores (vmcnt(0) before
    // s_barrier), so the overwrite is ordered after recon.
    const int cnt = scount;
    for (int i = 0; i < cnt; ++i) {
        const int row = m0 + slist[i];
        xs[tid] = images[(size_t)row * GDIM + tid];
        __syncthreads();
        // x2 in the proven g-ascending serial order
        float x2 = 0.f;
        for (int g = 0; g < GDIM; ++g) x2 += xs[g] * xs[g];
        // codes tid and tid+256: independent g-ascending fp32 chains
        float sA = 0.f, sB = 0.f;
        for (int g = 0; g < GDIM; ++g) {
            const float xv = xs[g];
            const float* mp = mu + (size_t)g * KDIM;
            sA += xv * mp[tid];
            sB += xv * mp[tid + 256];
        }
        const float dA = (x2 - 2.0f * sA) + m2g[tid];
        const float dB = (x2 - 2.0f * sB) + m2g[tid + 256];
        float bd = dA; int bk = tid;
        if (dB < bd) { bd = dB; bk = tid + 256; }      // strict < keeps lower k
        rsd[tid] = bd; rsk[tid] = bk;
        __syncthreads();
        for (int s = 128; s > 0; s >>= 1) {
            if (tid < s) {
                const float db = rsd[tid + s]; const int kb2 = rsk[tid + s];
                if (db < rsd[tid] || (db == rsd[tid] && kb2 < rsk[tid])) { rsd[tid] = db; rsk[tid] = kb2; }
            }
            __syncthreads();
        }
        const int kwin = rsk[0];
        out[(size_t)row * GDIM + tid] = muT[(size_t)kwin * GDIM + tid];
        __syncthreads();
    }
}

// ---------------- fallback (R1 kernel, no workspace) ----------------

constexpr int FROWS = 64, FXSTR = GDIM + 1;

__global__ __launch_bounds__(256)
void kmeans_fallback(const float* __restrict__ images, const float* __restrict__ mu,
                     float* __restrict__ out) {
    __shared__ float xsf[FROWS * FXSTR];
    __shared__ float m2s[KDIM];
    __shared__ float bd_s[4][FROWS];
    __shared__ int   bk_s[4][FROWS];
    __shared__ int   kbest_s[FROWS];
    const int tid = threadIdx.x;
    const long long b0 = (long long)blockIdx.x * FROWS;
    {
        const float4* img4 = (const float4*)(images + b0 * GDIM);
        #pragma unroll
        for (int i = 0; i < 16; ++i) {
            const int idx = tid + i * 256;
            const int r = idx >> 6, c = idx & 63;
            const float4 v = img4[idx];
            float* dst = &xsf[r * FXSTR + c * 4];
            dst[0] = v.x; dst[1] = v.y; dst[2] = v.z; dst[3] = v.w;
        }
    }
    {
        float s0 = 0.f, s1 = 0.f;
        for (int g = 0; g < GDIM; ++g) {
            const float a = mu[(size_t)g * KDIM + tid];
            const float b = mu[(size_t)g * KDIM + tid + 256];
            s0 += a * a; s1 += b * b;
        }
        m2s[tid] = s0; m2s[tid + 256] = s1;
    }
    __syncthreads();
    const int r = tid & (FROWS - 1), ch = tid >> 6;
    const float* xrow = &xsf[r * FXSTR];
    float x2 = 0.f;
    #pragma unroll 8
    for (int g = 0; g < GDIM; ++g) x2 += xrow[g] * xrow[g];
    float bestd = 3.402823466e+38f; int bestk = 0;
    const int k0base = ch * (KDIM / 4);
    for (int kt = 0; kt < KDIM / 4; kt += 8) {
        const int k0 = k0base + kt;
        float a8[8];
        #pragma unroll
        for (int j = 0; j < 8; ++j) a8[j] = 0.f;
        const float* mp = mu + k0;
        #pragma unroll 4
        for (int g = 0; g < GDIM; ++g) {
            const float xv = xrow[g];
            const float4 a = *(const float4*)(mp + (size_t)g * KDIM);
            const float4 b = *(const float4*)(mp + (size_t)g * KDIM + 4);
            a8[0] += xv * a.x; a8[1] += xv * a.y; a8[2] += xv * a.z; a8[3] += xv * a.w;
            a8[4] += xv * b.x; a8[5] += xv * b.y; a8[6] += xv * b.z; a8[7] += xv * b.w;
        }
        #pragma unroll
        for (int j = 0; j < 8; ++j) {
            const float t = x2 - 2.0f * a8[j];
            const float d = t + m2s[k0 + j];
            if (d < bestd) { bestd = d; bestk = k0 + j; }
        }
    }
    bd_s[ch][r] = bestd; bk_s[ch][r] = bestk;
    __syncthreads();
    if (tid < FROWS) {
        float bd = bd_s[0][tid]; int bk = bk_s[0][tid];
        #pragma unroll
        for (int c = 1; c < 4; ++c)
            if (bd_s[c][tid] < bd) { bd = bd_s[c][tid]; bk = bk_s[c][tid]; }
        kbest_s[tid] = bk;
    }
    __syncthreads();
    for (int i = tid; i < FROWS * GDIM; i += 256) {
        const int rr = i >> 8, gg = i & (GDIM - 1);
        out[b0 * GDIM + i] = mu[(size_t)gg * KDIM + kbest_s[rr]];
    }
}

// ---------------- launch ----------------

extern "C" void kernel_launch(void* const* d_in, const int* in_sizes, int n_in,
                              void* d_out, int out_size, void* d_ws, size_t ws_size,
                              hipStream_t stream) {
    const float* images = (const float*)d_in[0];
    const float* mu     = (const float*)d_in[1];
    float* out = (float*)d_out;

    float* ws     = (float*)d_ws;
    float* muT    = ws;                          // 131072 floats
    float* m2     = ws + 131072;                 // 512
    halfx8* packh = (halfx8*)(ws + 131584);      // 65536 floats (16384 vecs)
    halfx8* packl = (halfx8*)(ws + 197120);      // 65536 floats
    const size_t need = (size_t)262656 * sizeof(float);

    if (d_ws != nullptr && ws_size >= need) {
        prep_kernel<<<577, 256, 0, stream>>>(mu, muT, m2, packh, packl);
        gemm_argmin_mfma<<<NTILES, 256, 0, stream>>>(images, mu, packh, packl,
                                                     m2, muT, out);
    } else {
        kmeans_fallback<<<BATCH / 64, 256, 0, stream>>>(images, mu, out);
    }
}